// Round 4
// baseline (104.501 us; speedup 1.0000x reference)
//
#include <hip/hip_runtime.h>
#include <hip/hip_bf16.h>

#define BB 8
#define NN 256
#define DD 128
#define HH 512
#define LL 2
#define EPSV 1e-5f
#define TPB 8            // tokens per block
#define BPL (NN/TPB)     // pool partials per batch = 32

typedef unsigned short ushort_t;
typedef __attribute__((ext_vector_type(8))) short bf16x8;
typedef __attribute__((ext_vector_type(4))) float f32x4;

// converted-weight segment sizes (bf16 elements)
#define WPSZ (256*128)           // 32768
#define W1SZ (128*512)           // 65536
#define W2SZ (512*128)           // 65536
#define LAYSZ (WPSZ+W1SZ+W2SZ)   // 163840
#define TOTW (2*LAYSZ)           // 327680
#define WBLK 80                  // weight-conversion blocks (TOTW/8/512)

#if defined(__has_builtin)
#if __has_builtin(__builtin_amdgcn_sched_barrier)
#define SCHED_FENCE() __builtin_amdgcn_sched_barrier(0)
#endif
#endif
#ifndef SCHED_FENCE
#define SCHED_FENCE()
#endif

__device__ __forceinline__ ushort_t f2b(float v){
  __hip_bfloat16 h = __float2bfloat16(v);
  return *(ushort_t*)&h;
}

__device__ __forceinline__ void waveRed2(float &a, float &b){
  #pragma unroll
  for (int off=32; off>=1; off>>=1){
    a += __shfl_xor(a, off, 64);
    b += __shfl_xor(b, off, 64);
  }
}

__device__ __forceinline__ void poolMerge(float &m1, float &m2, int &am,
                                          float o1, float o2, int oa){
  if (o1 > m1){ m2 = fmaxf(m1, o2); m1 = o1; am = oa; }
  else        { m2 = fmaxf(m2, o1); }
}

// k_prep: blocks 0..79 convert all weights (both layers) from f32 [K][N]
// into bf16 fragment-ordered records (element off = rec*512 + lane*8 + j
// holds W[ks*32+(lane>>4)*8+j][n0t*16+(lane&15)], rec = n0t*(K/32)+ks).
// Blocks 80..87 (one per batch) compute the closed-form embed LN (9
// affine stats of We/be), materialize h0 for all 256 tokens to ws, and
// the fully-merged LOO pool (fm1/fm2/fam) per batch -- removing that
// work (replicated x32 blocks) from k_net(0)'s critical path.
__global__ __launch_bounds__(512) void k_prep(
    const float* __restrict__ Wp, const float* __restrict__ W1,
    const float* __restrict__ W2,
    const float* __restrict__ x, const float* __restrict__ We,
    const float* __restrict__ be, const float* __restrict__ ge,
    const float* __restrict__ bge,
    ushort_t* __restrict__ wcvt, float* __restrict__ h0w,
    float* __restrict__ fm1w, float* __restrict__ fm2w,
    int* __restrict__ famw)
{
  int tid = threadIdx.x;
  if (blockIdx.x < WBLK){
    int e8 = blockIdx.x*512 + tid;     // chunk index, 40960 total
    int e = e8*8;
    int l2 = (e >= LAYSZ) ? 1 : 0;
    int el = e - l2*LAYSZ;
    const float* src; int N, KSlog, off;
    if (el < WPSZ)           { src = Wp + (size_t)l2*WPSZ; N = 128; KSlog = 3; off = el; }
    else if (el < WPSZ+W1SZ) { src = W1 + (size_t)l2*W1SZ; N = 512; KSlog = 2; off = el - WPSZ; }
    else                     { src = W2 + (size_t)l2*W2SZ; N = 128; KSlog = 4; off = el - (WPSZ+W1SZ); }
    int rec  = off >> 9;
    int ln   = (off >> 3) & 63;
    int n0t  = rec >> KSlog;
    int ks   = rec & ((1<<KSlog)-1);
    int row0 = ks*32 + ((ln>>4)<<3);
    int col  = (n0t<<4) + (ln&15);
    bf16x8 v;
    #pragma unroll
    for (int j=0;j<8;++j) v[j] = (short)f2b(src[(size_t)(row0+j)*N + col]);
    *(bf16x8*)(wcvt + e) = v;
    return;
  }

  // ---- pool block: one per batch ----
  int bb = blockIdx.x - WBLK;
  int d = tid & 127, fourth = tid >> 7, lane = tid & 63;

  __shared__ float xs[512];
  __shared__ float red9[2][12];
  __shared__ float stats[12];
  __shared__ float4 tk[256];          // per-token (x0, x1, mean, rs)
  __shared__ float sm1[4][128], sm2[4][128];
  __shared__ int   sam[4][128];

  xs[tid] = x[(size_t)bb*512 + tid];
  float a = We[d], bw = We[128+d], c = be[d];
  if (fourth == 0){
    float r0=a, r1=bw;        waveRed2(r0,r1);
    float r2=c, r3=a*a;       waveRed2(r2,r3);
    float r4=bw*bw, r5=c*c;   waveRed2(r4,r5);
    float r6=a*bw, r7=a*c;    waveRed2(r6,r7);
    float r8=bw*c, r9=0.f;    waveRed2(r8,r9);
    int w = (tid >> 6) & 1;
    if (lane == 0){
      red9[w][0]=r0; red9[w][1]=r1; red9[w][2]=r2; red9[w][3]=r3;
      red9[w][4]=r4; red9[w][5]=r5; red9[w][6]=r6; red9[w][7]=r7;
      red9[w][8]=r8;
    }
  }
  __syncthreads();
  if (tid < 9) stats[tid] = (red9[0][tid] + red9[1][tid]) * (1.f/128);
  __syncthreads();
  if (tid < 256){
    float mA=stats[0], mB=stats[1], mC=stats[2];
    float SAA=stats[3], SBB=stats[4], SCC=stats[5];
    float SAB=stats[6], SAC=stats[7], SBC=stats[8];
    float x0 = xs[2*tid], x1 = xs[2*tid+1];
    float mean = fmaf(x0, mA, fmaf(x1, mB, mC));
    float ev2  = x0*x0*SAA + x1*x1*SBB + SCC
               + 2.f*(x0*x1*SAB + x0*SAC + x1*SBC);
    float var = ev2 - mean*mean;
    tk[tid] = make_float4(x0, x1, mean, rsqrtf(var + EPSV));
  }
  __syncthreads();
  float gev = ge[d], bgev = bge[d];
  // scan 64 tokens per (d, fourth); store h0 as we go (fire-and-forget)
  float m1=-3.4e38f, m2=-3.4e38f; int am=0;
  for (int i=0;i<64;++i){
    int n = fourth*64 + i;
    float4 t4 = tk[n];
    float v  = fmaf(t4.x, a, fmaf(t4.y, bw, c));
    float hv = fmaf((v - t4.z)*t4.w, gev, bgev);
    h0w[((size_t)bb*256 + n)*128 + d] = hv;
    poolMerge(m1,m2,am, hv, -3.4e38f, n);
  }
  sm1[fourth][d]=m1; sm2[fourth][d]=m2; sam[fourth][d]=am;
  __syncthreads();
  if (fourth==0){
    float M1=sm1[0][d], M2=sm2[0][d]; int AM=sam[0][d];
    #pragma unroll
    for (int p=1;p<4;++p) poolMerge(M1,M2,AM, sm1[p][d], sm2[p][d], sam[p][d]);
    fm1w[bb*128+d]=M1; fm2w[bb*128+d]=M2; famw[bb*128+d]=AM;
  }
}

// One kernel per layer, 256 blocks x 512 threads (1 block/CU, latency-
// bound serial chain). Layer 0 front end: load precomputed h0 + merged
// pool from ws, build both catb halves, ONE barrier (embed scan/stats/
// merges all moved to k_prep). Layer 1: partial merge path (depends on
// layer-0 output). Weights prefetched to registers at kernel top
// (stage C after stage-A MFMAs); LDS A-operands XOR-swizzled.
__global__ __launch_bounds__(512, 2) void k_net(
    int layer,
    float* __restrict__ hio,
    float* __restrict__ pm1, float* __restrict__ pm2, int* __restrict__ pma,
    const ushort_t* __restrict__ wL,
    const float* __restrict__ h0w, const float* __restrict__ fm1w,
    const float* __restrict__ fm2w, const int* __restrict__ famw,
    const float* __restrict__ bp,
    const float* __restrict__ gp, const float* __restrict__ bgp,
    const float* __restrict__ b1,
    const float* __restrict__ b2,
    const float* __restrict__ gf, const float* __restrict__ bgf)
{
  int tid = threadIdx.x;
  int d = tid & 127, fourth = tid >> 7;
  int wv = tid >> 6;            // wave 0..7
  int lane = tid & 63;
  int m = lane & 15, q = lane >> 4;
  int t0 = blockIdx.x * TPB;
  int b = t0 >> 8;
  int blk = (t0 >> 3) & (BPL-1);
  int n0a = wv*16;

  const ushort_t* wAb = wL;
  const ushort_t* wBb = wL + WPSZ;
  const ushort_t* wCb = wL + WPSZ + W1SZ;

  // ---- prefetch stage-A and stage-B weight fragments (96 VGPRs) ----
  bf16x8 wfa[8], wfb[16];
  #pragma unroll
  for (int ks=0; ks<8; ++ks)
    wfa[ks] = *(const bf16x8*)(wAb + ((size_t)(wv*8+ks)*64 + lane)*8);
  #pragma unroll
  for (int r=0; r<16; ++r)
    wfb[r] = *(const bf16x8*)(wBb + ((size_t)(((r>>2)*8+wv)*4 + (r&3))*64 + lane)*8);
  SCHED_FENCE();

  __shared__ float    hcur[8*128];    // 4K  h input for own 8 tokens (f32)
  __shared__ ushort_t catb[16*256];   // 8K  bf16 A-operand, stage A (swz)
  __shared__ float    sA[16*128];     // 8K  f32 GEMM out (A, then C)
  __shared__ ushort_t h1b[16*128];    // 4K  bf16 A-operand, stage B (swz)
  __shared__ float    h1f[8*128];     // 4K  f32 h1 (stage-C residual)
  __shared__ ushort_t ub[16*512];     // 16K bf16 A-operand, stage C (swz)
  __shared__ float fm1[128], fm2[128];
  __shared__ int   fam[128];
  __shared__ float sm1[4][128], sm2[4][128];
  __shared__ int   sam[4][128];

  if (layer == 0){
    // ---- own 8 tokens' h0 from ws (f32 + bf16 h-half of catb) ----
    #pragma unroll
    for (int rep=0; rep<2; ++rep){
      int t = fourth*2 + rep;
      float hv = h0w[(size_t)(t0+t)*DD + d];
      hcur[t*128 + d] = hv;
      *(ushort_t*)((char*)catb + (((t*256 + d)*2) ^ ((t&7)<<4))) = f2b(hv);
    }
    // ---- pooled half straight from the pre-merged global pool ----
    {
      int c2 = tid & 127;
      float f1  = fm1w[b*128 + c2];
      float f2v = fm2w[b*128 + c2];
      int   fa  = famw[b*128 + c2];
      #pragma unroll
      for (int rep=0; rep<2; ++rep){
        int e = rep*512 + tid;
        int t = e >> 7;
        int n = (t0 & 255) + t;
        float v = (n==fa) ? f2v : f1;
        *(ushort_t*)((char*)catb + (((t*256 + 128 + c2)*2) ^ ((t&7)<<4))) = f2b(v);
      }
    }
    __syncthreads();
  } else {
    // ---- merge the batch's 32 layer-0 pool partials (8 per fourth) ----
    {
      size_t base = ((size_t)b*BPL + fourth*8)*128 + d;
      float m1 = pm1[base], m2 = pm2[base]; int am = pma[base];
      #pragma unroll
      for (int i=1;i<8;++i)
        poolMerge(m1,m2,am, pm1[base+(size_t)i*128], pm2[base+(size_t)i*128],
                  pma[base+(size_t)i*128]);
      sm1[fourth][d]=m1; sm2[fourth][d]=m2; sam[fourth][d]=am;
    }
    // ---- own 8 tokens' h0 from hio (f32 + bf16 h-half of catb) ----
    #pragma unroll
    for (int rep=0; rep<2; ++rep){
      int t = fourth*2 + rep;
      float hv = hio[(size_t)(t0+t)*DD + d];
      hcur[t*128 + d] = hv;
      *(ushort_t*)((char*)catb + (((t*256 + d)*2) ^ ((t&7)<<4))) = f2b(hv);
    }
    __syncthreads();
    if (fourth==0){
      float m1=sm1[0][d], m2=sm2[0][d]; int am=sam[0][d];
      #pragma unroll
      for (int p=1;p<4;++p) poolMerge(m1,m2,am, sm1[p][d], sm2[p][d], sam[p][d]);
      fm1[d]=m1; fm2[d]=m2; fam[d]=am;
    }
    __syncthreads();
    // ---- pooled half catb[t][128..255] (swizzled) ----
    #pragma unroll
    for (int rep=0; rep<2; ++rep){
      int e = rep*512 + tid;
      int t = e >> 7, c2 = e & 127;
      int n = (t0 & 255) + t;
      float v = (n==fam[c2]) ? fm2[c2] : fm1[c2];
      *(ushort_t*)((char*)catb + (((t*256 + 128 + c2)*2) ^ ((t&7)<<4))) = f2b(v);
    }
    __syncthreads();
  }

  // ---- stage A: [16x128] = cat[16x256] @ Wp (weights pre-fetched) ----
  {
    f32x4 acc = {0.f,0.f,0.f,0.f};
    const char* apb = (const char*)catb;
    int abase = (m*256 + q*8)*2;
    int sw = (m&7)<<4;
    #pragma unroll
    for (int ks=0; ks<8; ++ks){
      bf16x8 af = *(const bf16x8*)(apb + ((abase + ks*64) ^ sw));
      acc = __builtin_amdgcn_mfma_f32_16x16x32_bf16(af, wfa[ks], acc, 0,0,0);
    }
    #pragma unroll
    for (int r=0;r<4;++r) sA[(q*4+r)*128 + n0a + m] = acc[r];
  }
  // ---- prefetch stage-C weight fragments (wfa now dead) ----
  bf16x8 wfc[16];
  #pragma unroll
  for (int kk=0; kk<16; ++kk)
    wfc[kk] = *(const bf16x8*)(wCb + ((size_t)(wv*16+kk)*64 + lane)*8);
  SCHED_FENCE();
  __syncthreads();

  // ---- LN-A: wave t = token t; lane handles d = 2g, 2g+1 ----
  {
    int t = wv, g = lane;
    float2 v2 = *(const float2*)&sA[t*128 + 2*g];
    float v0 = v2.x + bp[2*g]   + hcur[t*128 + 2*g];
    float v1 = v2.y + bp[2*g+1] + hcur[t*128 + 2*g + 1];
    float s = v0+v1, qq = v0*v0 + v1*v1;
    waveRed2(s,qq);
    float mean = s*(1.f/128), var = qq*(1.f/128) - mean*mean;
    float rs = rsqrtf(var + EPSV);
    float o0 = (v0-mean)*rs*gp[2*g]   + bgp[2*g];
    float o1 = (v1-mean)*rs*gp[2*g+1] + bgp[2*g+1];
    unsigned pk = (unsigned)f2b(o0) | ((unsigned)f2b(o1) << 16);
    *(unsigned*)((char*)h1b + (((t*128 + 2*g)*2) ^ ((t&7)<<4))) = pk;
    *(float2*)&h1f[t*128 + 2*g] = make_float2(o0, o1);
  }
  __syncthreads();

  // ---- stage B: [16x512] = h1[16x128] @ W1 (weights pre-fetched) ----
  {
    const char* apb = (const char*)h1b;
    int abase = (m*128 + q*8)*2;
    int sw = (m&7)<<4;
    bf16x8 af[4];
    #pragma unroll
    for (int ks=0; ks<4; ++ks)
      af[ks] = *(const bf16x8*)(apb + ((abase + ks*64) ^ sw));
    #pragma unroll
    for (int half=0; half<2; ++half){
      #pragma unroll
      for (int i=0;i<2;++i){
        int idx4 = half*2+i;
        int n0 = idx4*128 + wv*16;
        f32x4 acc = {0.f,0.f,0.f,0.f};
        #pragma unroll
        for (int ks=0; ks<4; ++ks)
          acc = __builtin_amdgcn_mfma_f32_16x16x32_bf16(af[ks], wfb[idx4*4+ks], acc, 0,0,0);
        float bb = b1[n0+m];
        #pragma unroll
        for (int r=0;r<4;++r){
          int row = q*4+r;
          *(ushort_t*)((char*)ub + (((row*512 + n0 + m)*2) ^ ((row&7)<<4)))
              = f2b(fmaxf(acc[r] + bb, 0.f));
        }
      }
    }
  }
  __syncthreads();

  // ---- stage C: [16x128] = u[16x512] @ W2 (weights pre-fetched) ----
  {
    f32x4 acc = {0.f,0.f,0.f,0.f};
    const char* apb = (const char*)ub;
    int abase = (m*512 + q*8)*2;
    int sw = (m&7)<<4;
    #pragma unroll
    for (int kk=0; kk<16; ++kk){
      bf16x8 af = *(const bf16x8*)(apb + ((abase + kk*64) ^ sw));
      acc = __builtin_amdgcn_mfma_f32_16x16x32_bf16(af, wfc[kk], acc, 0,0,0);
    }
    #pragma unroll
    for (int r=0;r<4;++r) sA[(q*4+r)*128 + n0a + m] = acc[r];
  }
  __syncthreads();

  // ---- LN-C: residual h1f -> hio (+ hcur for pool partial) ----
  {
    int t = wv, g = lane;
    float2 v2 = *(const float2*)&sA[t*128 + 2*g];
    float v0 = v2.x + b2[2*g]   + h1f[t*128 + 2*g];
    float v1 = v2.y + b2[2*g+1] + h1f[t*128 + 2*g + 1];
    float s = v0+v1, qq = v0*v0 + v1*v1;
    waveRed2(s,qq);
    float mean = s*(1.f/128), var = qq*(1.f/128) - mean*mean;
    float rs = rsqrtf(var + EPSV);
    float o0 = (v0-mean)*rs*gf[2*g]   + bgf[2*g];
    float o1 = (v1-mean)*rs*gf[2*g+1] + bgf[2*g+1];
    *(float2*)&hio[(size_t)(t0+t)*DD + 2*g] = make_float2(o0, o1);
    *(float2*)&hcur[t*128 + 2*g] = make_float2(o0, o1);
  }
  if (layer == 0){
    __syncthreads();
    if (tid < 128){
      int n0 = t0 & 255;
      float m1 = hcur[tid], m2 = -3.4e38f; int am = n0;
      #pragma unroll
      for (int p=1;p<TPB;++p)
        poolMerge(m1,m2,am, hcur[p*128+tid], -3.4e38f, n0+p);
      size_t idx = ((size_t)b*BPL + blk)*128 + tid;
      pm1[idx]=m1; pm2[idx]=m2; pma[idx]=am;
    }
  }
}

extern "C" void kernel_launch(void* const* d_in, const int* in_sizes, int n_in,
                              void* d_out, int out_size, void* d_ws, size_t ws_size,
                              hipStream_t stream)
{
  const float* x   = (const float*)d_in[0];
  const float* We  = (const float*)d_in[1];
  const float* be  = (const float*)d_in[2];
  const float* ge  = (const float*)d_in[3];
  const float* bge = (const float*)d_in[4];
  const float* Wp  = (const float*)d_in[5];
  const float* bp  = (const float*)d_in[6];
  const float* gp  = (const float*)d_in[7];
  const float* bgp = (const float*)d_in[8];
  const float* W1  = (const float*)d_in[9];
  const float* b1  = (const float*)d_in[10];
  const float* W2  = (const float*)d_in[11];
  const float* b2  = (const float*)d_in[12];
  const float* gf  = (const float*)d_in[13];
  const float* bgf = (const float*)d_in[14];

  float* hio = (float*)d_out;
  char* ws = (char*)d_ws;
  const size_t NP = (size_t)BB*BPL*128;     // 32768
  float* p1 = (float*)ws;            ws += NP*4;
  float* p2 = (float*)ws;            ws += NP*4;
  int*   pa = (int*)ws;              ws += NP*4;
  ushort_t* wcvt = (ushort_t*)ws;    ws += (size_t)TOTW*2;
  float* h0w  = (float*)ws;          ws += (size_t)BB*NN*DD*4;
  float* fm1w = (float*)ws;          ws += (size_t)BB*128*4;
  float* fm2w = (float*)ws;          ws += (size_t)BB*128*4;
  int*   famw = (int*)ws;            ws += (size_t)BB*128*4;

  const int grid = (BB*NN)/TPB;   // 256

  k_prep<<<WBLK + BB, 512, 0, stream>>>(Wp, W1, W2, x, We, be, ge, bge,
                                        wcvt, h0w, fm1w, fm2w, famw);

  k_net<<<grid, 512, 0, stream>>>(0, hio, p1, p2, pa,
      wcvt, h0w, fm1w, fm2w, famw,
      bp,      gp,      bgp,
      b1,      b2,
      gf,      bgf);

  k_net<<<grid, 512, 0, stream>>>(1, hio, p1, p2, pa,
      wcvt + LAYSZ, h0w, fm1w, fm2w, famw,
      bp + DD, gp + DD, bgp + DD,
      b1 + HH, b2 + DD,
      gf + DD, bgf + DD);
}